// Round 11
// baseline (156.686 us; speedup 1.0000x reference)
//
#include <hip/hip_runtime.h>
#include <hip/hip_bf16.h>

#define DEVI static __device__ __forceinline__

typedef __attribute__((ext_vector_type(8))) short bf16x8;
typedef __attribute__((ext_vector_type(4))) float f32x4;
typedef __attribute__((ext_vector_type(16))) float f32x16;
typedef __attribute__((ext_vector_type(4))) int i32x4;

constexpr int Bc = 4, Nc = 2048, Cc = 768, Hc = 12, Dhc = 64;
constexpr int Mc = Bc * Nc;   // 8192 tokens
constexpr int K3c = 3 * Cc;   // 2304

// fp32 -> bf16 round-to-nearest-even
DEVI unsigned int f2bf(float f) {
  unsigned int u = __float_as_uint(f);
  return (u + 0x7fffu + ((u >> 16) & 1u)) >> 16;
}
DEVI float bf2f(unsigned int u) { return __uint_as_float(u << 16); }

DEVI unsigned int cvtpk_bf16(float lo, float hi_) {
  unsigned int r;
  asm("v_cvt_pk_bf16_f32 %0, %1, %2" : "=v"(r) : "v"(lo), "v"(hi_));
  return r;
}

// Raw v_exp_f32 (2^x) — libm exp2f is a multi-inst OCML routine (round-4 bug).
#if __has_builtin(__builtin_amdgcn_exp2f)
#define EXP2(x) __builtin_amdgcn_exp2f(x)
#else
#define EXP2(x) exp2f(x)
#endif

#define GLOAD_LDS(g, l)                                                              \
  __builtin_amdgcn_global_load_lds((const __attribute__((address_space(1))) void*)(g), \
                                   (__attribute__((address_space(3))) void*)(l), 16, 0, 0)

// rope on a packed bf16 pair word
DEVI unsigned int rope_pair(unsigned int w, float c, float s) {
  const float a = bf2f(w & 0xffffu), b_ = bf2f(w >> 16);
  return f2bf(a * c - b_ * s) | (f2bf(a * s + b_ * c) << 16);
}

// ---------------------------------------------------------------------------
// fp32 -> bf16 bulk convert, 8 elems/thread
// ---------------------------------------------------------------------------
__global__ __launch_bounds__(256) void cvt_f32_bf16(const float* __restrict__ in,
                                                    unsigned short* __restrict__ out, int n8) {
  const int i = blockIdx.x * 256 + threadIdx.x;
  if (i >= n8) return;
  const f32x4 a = *((const f32x4*)in + (size_t)i * 2);
  const f32x4 b = *((const f32x4*)in + (size_t)i * 2 + 1);
  i32x4 v;
  v.x = (int)(f2bf(a.x) | (f2bf(a.y) << 16));
  v.y = (int)(f2bf(a.z) | (f2bf(a.w) << 16));
  v.z = (int)(f2bf(b.x) | (f2bf(b.y) << 16));
  v.w = (int)(f2bf(b.z) | (f2bf(b.w) << 16));
  *((i32x4*)out + i) = v;
}

// ---------------------------------------------------------------------------
// GEMM: C[M,Nout] = A[M,K] * W[Nout,K]^T, bf16 in. 128x128 tile, BK=64,
// 4 waves (2x2), mfma 16x16x32, global_load_lds staging. (unchanged — passing)
// ---------------------------------------------------------------------------
template <int OBF16>
__global__ __launch_bounds__(256) void gemm_bt16(const unsigned short* __restrict__ Ap,
                                                 const unsigned short* __restrict__ Wp,
                                                 void* __restrict__ Cp,
                                                 const float* __restrict__ bias,
                                                 int Nout, int Kdim) {
  __shared__ unsigned short As[128 * 64];
  __shared__ unsigned short Bs[128 * 64];
  const int tid = threadIdx.x;
  const int bn = blockIdx.x, bm = blockIdx.y;
  const int m0 = bm * 128, n0 = bn * 128;
  const int w = tid >> 6, lane = tid & 63;
  const int wr = w >> 1, wc = w & 1;
  const int lr = lane & 15, lg = lane >> 4;
  const int r = lane >> 3, slot = lane & 7;

  f32x4 acc[4][4];
#pragma unroll
  for (int i = 0; i < 4; ++i)
#pragma unroll
    for (int j = 0; j < 4; ++j) acc[i][j] = f32x4{0.f, 0.f, 0.f, 0.f};

  for (int kt = 0; kt < Kdim; kt += 64) {
    __syncthreads();
#pragma unroll
    for (int c = 0; c < 4; ++c) {
      const int i = (w << 2) + c;
      const int row = (i << 3) + r;
      const unsigned short* ga = Ap + (size_t)(m0 + row) * Kdim + kt + ((slot ^ r) << 3);
      GLOAD_LDS(ga, As + (i << 9));
      const unsigned short* gb = Wp + (size_t)(n0 + row) * Kdim + kt + ((slot ^ r) << 3);
      GLOAD_LDS(gb, Bs + (i << 9));
    }
    __syncthreads();

    bf16x8 af[4][2], bfr[4][2];
#pragma unroll
    for (int mf = 0; mf < 4; ++mf) {
      const int row = wr * 64 + mf * 16 + lr;
#pragma unroll
      for (int kk = 0; kk < 2; ++kk)
        af[mf][kk] = *(const bf16x8*)&As[row * 64 + (((kk * 4 + lg) ^ (row & 7)) * 8)];
    }
#pragma unroll
    for (int nf = 0; nf < 4; ++nf) {
      const int row = wc * 64 + nf * 16 + lr;
#pragma unroll
      for (int kk = 0; kk < 2; ++kk)
        bfr[nf][kk] = *(const bf16x8*)&Bs[row * 64 + (((kk * 4 + lg) ^ (row & 7)) * 8)];
    }
#pragma unroll
    for (int mf = 0; mf < 4; ++mf)
#pragma unroll
      for (int nf = 0; nf < 4; ++nf)
#pragma unroll
        for (int kk = 0; kk < 2; ++kk)
          acc[mf][nf] = __builtin_amdgcn_mfma_f32_16x16x32_bf16(af[mf][kk], bfr[nf][kk],
                                                                acc[mf][nf], 0, 0, 0);
  }

#pragma unroll
  for (int mf = 0; mf < 4; ++mf) {
#pragma unroll
    for (int nf = 0; nf < 4; ++nf) {
      const int col = n0 + wc * 64 + nf * 16 + lr;
#pragma unroll
      for (int rg = 0; rg < 4; ++rg) {
        const int rowg = m0 + wr * 64 + mf * 16 + lg * 4 + rg;
        const float v = acc[mf][nf][rg];
        if constexpr (OBF16) {
          ((unsigned short*)Cp)[(size_t)rowg * Nout + col] = (unsigned short)f2bf(v);
        } else {
          ((float*)Cp)[(size_t)rowg * Nout + col] = v + bias[col];
        }
      }
    }
  }
}

// ---------------------------------------------------------------------------
// RoPE for Q only: qkv [B,N,3,H,Dh] bf16 -> Q [B,H,N,Dh] bf16, pre-scaled
// by KL = (1/sqrt(Dh))*log2(e). (K handled in pack_kv.)
// ---------------------------------------------------------------------------
__global__ __launch_bounds__(256) void rope_q(const unsigned short* __restrict__ qkv,
                                              const float* __restrict__ fcos,
                                              const float* __restrict__ fsin,
                                              unsigned short* __restrict__ Qo) {
  constexpr float KL = 0.18033688011112042f;  // (1/sqrt(64)) * log2(e)
  const int idx = blockIdx.x * 256 + threadIdx.x;
  if (idx >= Bc * Nc * Hc * 32) return;
  const int dp = idx & 31;
  const int t = idx >> 5;
  const int h = t % Hc;
  const int bn = t / Hc;
  const int n = bn & (Nc - 1);
  const int b = bn >> 11;
  const size_t qoff = (size_t)bn * 3 * Cc + h * 64 + dp * 2;
  const unsigned int qp = *(const unsigned int*)&qkv[qoff];
  const float c = fcos[n * 32 + dp], s = fsin[n * 32 + dp];
  const float qa = bf2f(qp & 0xffffu), qb = bf2f(qp >> 16);
  const unsigned int qo = f2bf(KL * (qa * c - qb * s)) | (f2bf(KL * (qa * s + qb * c)) << 16);
  const size_t o = ((size_t)((b * Hc + h) * Nc) + n) * Dhc + dp * 2;
  *(unsigned int*)&Qo[o] = qo;
}

// ---------------------------------------------------------------------------
// pack_kv: per (bh, 64-n tile) build the COALESCED attention layouts:
//   Kc[bh][ch=0..7][n][8]  (d-chunk-major K, rope applied here)
//   Vc[bh][g=n>>3][d][8]   (kv-chunk-major V^T)
// ---------------------------------------------------------------------------
__global__ __launch_bounds__(256) void pack_kv(const unsigned short* __restrict__ qkv,
                                               const float* __restrict__ fcos,
                                               const float* __restrict__ fsin,
                                               unsigned short* __restrict__ Kc,
                                               unsigned short* __restrict__ Vc) {
  __shared__ unsigned short kt[64 * 72];  // rows padded to 72 shorts
  __shared__ unsigned short vt[64 * 72];
  const int nt = blockIdx.x, bh = blockIdx.y;
  const int b = bh / Hc, h = bh % Hc;
  const int n0 = nt * 64;
  const int tid = threadIdx.x;
  const int nl = tid >> 3, slot = tid & 7;

#pragma unroll
  for (int it = 0; it < 2; ++it) {
    const int n = it * 32 + nl;
    const size_t base = (size_t)(b * Nc + n0 + n) * K3c + h * 64 + slot * 8;
    i32x4 vv = *(const i32x4*)&qkv[base + 2 * Cc];
    *(i32x4*)&vt[n * 72 + slot * 8] = vv;
    i32x4 kv = *(const i32x4*)&qkv[base + Cc];
    const f32x4 cv = *(const f32x4*)&fcos[(n0 + n) * 32 + slot * 4];
    const f32x4 sv = *(const f32x4*)&fsin[(n0 + n) * 32 + slot * 4];
    i32x4 ko;
    ko.x = (int)rope_pair((unsigned int)kv.x, cv.x, sv.x);
    ko.y = (int)rope_pair((unsigned int)kv.y, cv.y, sv.y);
    ko.z = (int)rope_pair((unsigned int)kv.z, cv.z, sv.z);
    ko.w = (int)rope_pair((unsigned int)kv.w, cv.w, sv.w);
    *(i32x4*)&kt[n * 72 + slot * 8] = ko;
  }
  __syncthreads();

#pragma unroll
  for (int it = 0; it < 2; ++it) {
    const int task = it * 256 + tid;
    const int g = task >> 6;       // 0..7
    const int d = task & 63;       // 0..63
    unsigned short tmpv[8];
#pragma unroll
    for (int j = 0; j < 8; ++j) tmpv[j] = vt[(g * 8 + j) * 72 + d];
    *(i32x4*)&Vc[(((size_t)bh * 256 + (n0 >> 3) + g) * 64 + d) * 8] = *(const i32x4*)tmpv;
    *(i32x4*)&Kc[(((size_t)bh * 8 + g) * Nc + n0 + d) * 8] = *(const i32x4*)&kt[d * 72 + g * 8];
  }
}

// ---------------------------------------------------------------------------
// Causal flash attention — SERIAL MIRROR PAIRS.
// Each wave owns segments s and 63-s, processed SEQUENTIALLY (full pass +
// epilogue each; only one segment's state live -> VGPR ~80). Iterations
// per wave = (floor(s/2)+1) + (floor((63-s)/2)+1) = 33, CONSTANT for all s
// -> every one of the 1536 waves is equal-length, so ANY work-conserving
// dispatch is balanced (rounds 6-10 all lost to makespan = longest wave;
// there is no backfill since the whole grid is co-resident).
// 2-wave blocks pair s=2t,2t+1: phase-A iteration counts are both t+1 and
// phase-B both 32-t -> the pair walks the same kv tiles in lockstep through
// both phases -> L1 KV sharing preserved. bh XCD-pinned via id&7.
// ---------------------------------------------------------------------------
__global__ __launch_bounds__(128, 3) void attn_fwd(const unsigned short* __restrict__ Qp,
                                                   const unsigned short* __restrict__ Kcp,
                                                   const unsigned short* __restrict__ Vcp,
                                                   unsigned short* __restrict__ Op) {
  const int id = blockIdx.x;
  const int x8 = id & 7;
  const int rr_ = id >> 3;              // 0..95
  const int t = rr_ / 6;                // 0..15 pair-group
  const int bh = x8 + ((rr_ % 6) << 3);
  const int wv = threadIdx.x >> 6, lane = threadIdx.x & 63;
  const int qc = lane & 31, hi = lane >> 5;
  const int s0 = 2 * t + wv;            // 0..31
  const unsigned short* Kcb = Kcp + (size_t)bh * (8 * Nc * 8);
  const unsigned short* Vcb = Vcp + (size_t)bh * (256 * 64 * 8);
  const int b = bh / Hc, h = bh % Hc;

  for (int phase = 0; phase < 2; ++phase) {
    const int s = phase ? (63 - s0) : s0;
    const int qw0 = s * 32;             // segment's first q-row
    const int qrow = qw0 + qc;          // this lane's q index

    bf16x8 qf[4];
    {
      const unsigned short* qptr = Qp + ((size_t)bh * Nc + qrow) * 64 + hi * 8;
#pragma unroll
      for (int ks = 0; ks < 4; ++ks) qf[ks] = *(const bf16x8*)(qptr + ks * 16);
    }

    f32x16 oacc[2];
#pragma unroll
    for (int dt = 0; dt < 2; ++dt)
#pragma unroll
      for (int j = 0; j < 16; ++j) oacc[dt][j] = 0.f;
    float m_run = -1e30f, l_run = 0.f;

    for (int k0 = 0; k0 <= qw0 + 31; k0 += 64) {
      // --- K fragments (coalesced; block's 2 waves issue the same addrs)
      bf16x8 kf[2][4];
#pragma unroll
      for (int f = 0; f < 2; ++f)
#pragma unroll
        for (int ks = 0; ks < 4; ++ks)
          kf[f][ks] = *(const bf16x8*)&Kcb[(((2 * ks + hi) * Nc) + k0 + f * 32 + qc) * 8];

      // --- V fragments (coalesced), issued before QK^T so latency hides
      bf16x8 vf[2][4];
#pragma unroll
      for (int dt = 0; dt < 2; ++dt)
#pragma unroll
        for (int ks = 0; ks < 4; ++ks)
          vf[dt][ks] = *(const bf16x8*)&Vcb[(((k0 >> 3) + 2 * ks + hi) * 64 + dt * 32 + qc) * 8];

      // --- QK^T : S^T[kv][q] (already in exp2 domain; Q pre-scaled)
      f32x16 sacc[2];
#pragma unroll
      for (int f = 0; f < 2; ++f)
#pragma unroll
        for (int j = 0; j < 16; ++j) sacc[f][j] = 0.f;
#pragma unroll
      for (int f = 0; f < 2; ++f)
#pragma unroll
        for (int ks = 0; ks < 4; ++ks)
          sacc[f] = __builtin_amdgcn_mfma_f32_32x32x16_bf16(kf[f][ks], qf[ks], sacc[f], 0, 0, 0);

      // --- causal mask folded; lane kv row: f*32+(rr&3)+8*(rr>>2)+4*hi
      if (k0 + 63 > qw0) {
#pragma unroll
        for (int f = 0; f < 2; ++f)
#pragma unroll
          for (int rr = 0; rr < 16; ++rr) {
            const int kvi = k0 + f * 32 + (rr & 3) + ((rr >> 2) << 3) + (hi << 2);
            if (kvi > qrow) sacc[f][rr] = -1e30f;
          }
      }

      // --- online softmax: tree max
      float mx[16];
#pragma unroll
      for (int j = 0; j < 16; ++j) mx[j] = fmaxf(sacc[0][j], sacc[1][j]);
#pragma unroll
      for (int st = 8; st >= 1; st >>= 1)
#pragma unroll
        for (int j = 0; j < st; ++j) mx[j] = fmaxf(mx[j], mx[j + st]);
      const float pmax = fmaxf(mx[0], __shfl_xor(mx[0], 32, 64));

      if (!__all(pmax - m_run <= 11.5f)) {  // defer-max (T13)
        const float m_new = fmaxf(m_run, pmax);
        const float rs = EXP2(m_run - m_new);
        l_run *= rs;
#pragma unroll
        for (int dt = 0; dt < 2; ++dt)
#pragma unroll
          for (int j = 0; j < 16; ++j) oacc[dt][j] *= rs;
        m_run = m_new;
      }

      // --- P = exp2(S - m); masked entries underflow to 0
      float p[32];
#pragma unroll
      for (int f = 0; f < 2; ++f)
#pragma unroll
        for (int rr = 0; rr < 16; ++rr) p[f * 16 + rr] = EXP2(sacc[f][rr] - m_run);

      // tree sum
      float ts[16];
#pragma unroll
      for (int j = 0; j < 16; ++j) ts[j] = p[j] + p[16 + j];
#pragma unroll
      for (int st = 8; st >= 1; st >>= 1)
#pragma unroll
        for (int j = 0; j < st; ++j) ts[j] += ts[j + st];
      l_run += ts[0] + __shfl_xor(ts[0], 32, 64);

      unsigned int pw[2][8];
#pragma unroll
      for (int f = 0; f < 2; ++f) {
#pragma unroll
        for (int j = 0; j < 8; ++j)
          pw[f][j] = cvtpk_bf16(p[f * 16 + 2 * j], p[f * 16 + 2 * j + 1]);
        // T12: earlier-kv word is vdst (vdst[32:63] <-> vsrc[0:31])
        asm volatile("v_permlane32_swap_b32 %0, %1" : "+v"(pw[f][0]), "+v"(pw[f][2]));
        asm volatile("v_permlane32_swap_b32 %0, %1" : "+v"(pw[f][1]), "+v"(pw[f][3]));
        asm volatile("v_permlane32_swap_b32 %0, %1" : "+v"(pw[f][4]), "+v"(pw[f][6]));
        asm volatile("v_permlane32_swap_b32 %0, %1" : "+v"(pw[f][5]), "+v"(pw[f][7]));
      }

      // --- PV: O^T[d][q] += V^T x P
#pragma unroll
      for (int dt = 0; dt < 2; ++dt)
#pragma unroll
        for (int ks = 0; ks < 4; ++ks) {
          i32x4 pi;
          pi.x = (int)pw[ks >> 1][(ks & 1) * 4 + 0];
          pi.y = (int)pw[ks >> 1][(ks & 1) * 4 + 1];
          pi.z = (int)pw[ks >> 1][(ks & 1) * 4 + 2];
          pi.w = (int)pw[ks >> 1][(ks & 1) * 4 + 3];
          bf16x8 pf = __builtin_bit_cast(bf16x8, pi);
          oacc[dt] = __builtin_amdgcn_mfma_f32_32x32x16_bf16(vf[dt][ks], pf, oacc[dt], 0, 0, 0);
        }
    }

    // --- epilogue: lane owns q column; d = dt*32 + rq*8 + hi*4 + (0..3)
    const float inv = 1.f / l_run;
    unsigned short* orow = Op + ((size_t)(b * Nc + qrow)) * Cc + h * 64;
#pragma unroll
    for (int dt = 0; dt < 2; ++dt)
#pragma unroll
      for (int rq = 0; rq < 4; ++rq) {
        const float o0 = oacc[dt][rq * 4 + 0] * inv;
        const float o1 = oacc[dt][rq * 4 + 1] * inv;
        const float o2 = oacc[dt][rq * 4 + 2] * inv;
        const float o3 = oacc[dt][rq * 4 + 3] * inv;
        uint2 val;
        val.x = f2bf(o0) | (f2bf(o1) << 16);
        val.y = f2bf(o2) | (f2bf(o3) << 16);
        *(uint2*)(orow + dt * 32 + rq * 8 + hi * 4) = val;
      }
  }
}

// ---------------------------------------------------------------------------
// Workspace layout (75,497,472 B total):
//   [0,       37.75M) qkv bf16          (later reused as attn output)
//   [37.75M, +12.58M) x_bf16, then Q    (x dead before rope_q writes Q)
//   [50.33M, +12.58M) wqkv_bf16, then Kc (wqkv dead before pack_kv)
//   [62.91M, +12.58M) Vc, then wproj_bf16 after attn consumes Vc
// ---------------------------------------------------------------------------
extern "C" void kernel_launch(void* const* d_in, const int* in_sizes, int n_in,
                              void* d_out, int out_size, void* d_ws, size_t ws_size,
                              hipStream_t stream) {
  const float* x = (const float*)d_in[0];
  const float* fcos = (const float*)d_in[1];
  const float* fsin = (const float*)d_in[2];
  // d_in[3] (mask) unused: causal structure applied analytically
  const float* wqkv = (const float*)d_in[4];
  const float* wproj = (const float*)d_in[5];
  const float* bproj = (const float*)d_in[6];

  char* ws = (char*)d_ws;
  unsigned short* qkvb = (unsigned short*)ws;
  unsigned short* Qb = (unsigned short*)(ws + 37748736);
  unsigned short* Kcb = (unsigned short*)(ws + 37748736 + 12582912);
  unsigned short* Vcb = (unsigned short*)(ws + 37748736 + 2 * 12582912);
  unsigned short* xb = Qb;
  unsigned short* wqkvb = Kcb;
  unsigned short* wprojb = Vcb;
  unsigned short* attnb = qkvb;

  // 0. fp32 -> bf16 converts
  cvt_f32_bf16<<<dim3(786432 / 256), 256, 0, stream>>>(x, xb, 786432);
  cvt_f32_bf16<<<dim3(221184 / 256), 256, 0, stream>>>(wqkv, wqkvb, 221184);
  // 1. qkv = x @ w_qkv^T (bf16 out)
  gemm_bt16<1><<<dim3(K3c / 128, Mc / 128), 256, 0, stream>>>(xb, wqkvb, qkvb, nullptr,
                                                              K3c, Cc);
  // 2. RoPE -> Q [B,H,N,Dh] (pre-scaled by KL)
  rope_q<<<dim3(Bc * Nc * Hc * 32 / 256), 256, 0, stream>>>(qkvb, fcos, fsin, Qb);
  // 3. K-rope + chunk-major packs -> Kc, Vc
  pack_kv<<<dim3(Nc / 64, Bc * Hc), 256, 0, stream>>>(qkvb, fcos, fsin, Kcb, Vcb);
  // 4. causal attention -> attnb (768 blocks; every wave = 33 iterations)
  attn_fwd<<<dim3(768), 128, 0, stream>>>(Qb, Kcb, Vcb, attnb);
  // 5. out = attn @ w_proj^T + b (fp32 out)
  cvt_f32_bf16<<<dim3(73728 / 256), 256, 0, stream>>>(wproj, wprojb, 73728);
  gemm_bt16<0><<<dim3(Cc / 128, Mc / 128), 256, 0, stream>>>(attnb, wprojb, d_out, bproj,
                                                             Cc, Cc);
}

// Round 12
// 153.243 us; speedup vs baseline: 1.0225x; 1.0225x over previous
//
#include <hip/hip_runtime.h>
#include <hip/hip_bf16.h>

#define DEVI static __device__ __forceinline__

typedef __attribute__((ext_vector_type(8))) short bf16x8;
typedef __attribute__((ext_vector_type(4))) float f32x4;
typedef __attribute__((ext_vector_type(16))) float f32x16;
typedef __attribute__((ext_vector_type(4))) int i32x4;

constexpr int Bc = 4, Nc = 2048, Cc = 768, Hc = 12, Dhc = 64;
constexpr int Mc = Bc * Nc;   // 8192 tokens
constexpr int K3c = 3 * Cc;   // 2304

// fp32 -> bf16 round-to-nearest-even
DEVI unsigned int f2bf(float f) {
  unsigned int u = __float_as_uint(f);
  return (u + 0x7fffu + ((u >> 16) & 1u)) >> 16;
}
DEVI float bf2f(unsigned int u) { return __uint_as_float(u << 16); }

DEVI unsigned int cvtpk_bf16(float lo, float hi_) {
  unsigned int r;
  asm("v_cvt_pk_bf16_f32 %0, %1, %2" : "=v"(r) : "v"(lo), "v"(hi_));
  return r;
}

// Raw v_exp_f32 (2^x) — libm exp2f is a multi-inst OCML routine (round-4 bug).
#if __has_builtin(__builtin_amdgcn_exp2f)
#define EXP2(x) __builtin_amdgcn_exp2f(x)
#else
#define EXP2(x) exp2f(x)
#endif

#define GLOAD_LDS(g, l)                                                              \
  __builtin_amdgcn_global_load_lds((const __attribute__((address_space(1))) void*)(g), \
                                   (__attribute__((address_space(3))) void*)(l), 16, 0, 0)

// rope on a packed bf16 pair word
DEVI unsigned int rope_pair(unsigned int w, float c, float s) {
  const float a = bf2f(w & 0xffffu), b_ = bf2f(w >> 16);
  return f2bf(a * c - b_ * s) | (f2bf(a * s + b_ * c) << 16);
}

// ---------------------------------------------------------------------------
// fp32 -> bf16 bulk convert, 8 elems/thread
// ---------------------------------------------------------------------------
__global__ __launch_bounds__(256) void cvt_f32_bf16(const float* __restrict__ in,
                                                    unsigned short* __restrict__ out, int n8) {
  const int i = blockIdx.x * 256 + threadIdx.x;
  if (i >= n8) return;
  const f32x4 a = *((const f32x4*)in + (size_t)i * 2);
  const f32x4 b = *((const f32x4*)in + (size_t)i * 2 + 1);
  i32x4 v;
  v.x = (int)(f2bf(a.x) | (f2bf(a.y) << 16));
  v.y = (int)(f2bf(a.z) | (f2bf(a.w) << 16));
  v.z = (int)(f2bf(b.x) | (f2bf(b.y) << 16));
  v.w = (int)(f2bf(b.z) | (f2bf(b.w) << 16));
  *((i32x4*)out + i) = v;
}

// ---------------------------------------------------------------------------
// GEMM: C[M,Nout] = A[M,K] * W[Nout,K]^T, bf16 in. 128x128 tile, BK=64,
// 4 waves (2x2), mfma 16x16x32, global_load_lds staging. (unchanged — passing)
// ---------------------------------------------------------------------------
template <int OBF16>
__global__ __launch_bounds__(256) void gemm_bt16(const unsigned short* __restrict__ Ap,
                                                 const unsigned short* __restrict__ Wp,
                                                 void* __restrict__ Cp,
                                                 const float* __restrict__ bias,
                                                 int Nout, int Kdim) {
  __shared__ unsigned short As[128 * 64];
  __shared__ unsigned short Bs[128 * 64];
  const int tid = threadIdx.x;
  const int bn = blockIdx.x, bm = blockIdx.y;
  const int m0 = bm * 128, n0 = bn * 128;
  const int w = tid >> 6, lane = tid & 63;
  const int wr = w >> 1, wc = w & 1;
  const int lr = lane & 15, lg = lane >> 4;
  const int r = lane >> 3, slot = lane & 7;

  f32x4 acc[4][4];
#pragma unroll
  for (int i = 0; i < 4; ++i)
#pragma unroll
    for (int j = 0; j < 4; ++j) acc[i][j] = f32x4{0.f, 0.f, 0.f, 0.f};

  for (int kt = 0; kt < Kdim; kt += 64) {
    __syncthreads();
#pragma unroll
    for (int c = 0; c < 4; ++c) {
      const int i = (w << 2) + c;
      const int row = (i << 3) + r;
      const unsigned short* ga = Ap + (size_t)(m0 + row) * Kdim + kt + ((slot ^ r) << 3);
      GLOAD_LDS(ga, As + (i << 9));
      const unsigned short* gb = Wp + (size_t)(n0 + row) * Kdim + kt + ((slot ^ r) << 3);
      GLOAD_LDS(gb, Bs + (i << 9));
    }
    __syncthreads();

    bf16x8 af[4][2], bfr[4][2];
#pragma unroll
    for (int mf = 0; mf < 4; ++mf) {
      const int row = wr * 64 + mf * 16 + lr;
#pragma unroll
      for (int kk = 0; kk < 2; ++kk)
        af[mf][kk] = *(const bf16x8*)&As[row * 64 + (((kk * 4 + lg) ^ (row & 7)) * 8)];
    }
#pragma unroll
    for (int nf = 0; nf < 4; ++nf) {
      const int row = wc * 64 + nf * 16 + lr;
#pragma unroll
      for (int kk = 0; kk < 2; ++kk)
        bfr[nf][kk] = *(const bf16x8*)&Bs[row * 64 + (((kk * 4 + lg) ^ (row & 7)) * 8)];
    }
#pragma unroll
    for (int mf = 0; mf < 4; ++mf)
#pragma unroll
      for (int nf = 0; nf < 4; ++nf)
#pragma unroll
        for (int kk = 0; kk < 2; ++kk)
          acc[mf][nf] = __builtin_amdgcn_mfma_f32_16x16x32_bf16(af[mf][kk], bfr[nf][kk],
                                                                acc[mf][nf], 0, 0, 0);
  }

#pragma unroll
  for (int mf = 0; mf < 4; ++mf) {
#pragma unroll
    for (int nf = 0; nf < 4; ++nf) {
      const int col = n0 + wc * 64 + nf * 16 + lr;
#pragma unroll
      for (int rg = 0; rg < 4; ++rg) {
        const int rowg = m0 + wr * 64 + mf * 16 + lg * 4 + rg;
        const float v = acc[mf][nf][rg];
        if constexpr (OBF16) {
          ((unsigned short*)Cp)[(size_t)rowg * Nout + col] = (unsigned short)f2bf(v);
        } else {
          ((float*)Cp)[(size_t)rowg * Nout + col] = v + bias[col];
        }
      }
    }
  }
}

// ---------------------------------------------------------------------------
// RoPE for Q only: qkv [B,N,3,H,Dh] bf16 -> Q [B,H,N,Dh] bf16, pre-scaled
// by KL = (1/sqrt(Dh))*log2(e). (K handled in pack_kv.)
// ---------------------------------------------------------------------------
__global__ __launch_bounds__(256) void rope_q(const unsigned short* __restrict__ qkv,
                                              const float* __restrict__ fcos,
                                              const float* __restrict__ fsin,
                                              unsigned short* __restrict__ Qo) {
  constexpr float KL = 0.18033688011112042f;  // (1/sqrt(64)) * log2(e)
  const int idx = blockIdx.x * 256 + threadIdx.x;
  if (idx >= Bc * Nc * Hc * 32) return;
  const int dp = idx & 31;
  const int t = idx >> 5;
  const int h = t % Hc;
  const int bn = t / Hc;
  const int n = bn & (Nc - 1);
  const int b = bn >> 11;
  const size_t qoff = (size_t)bn * 3 * Cc + h * 64 + dp * 2;
  const unsigned int qp = *(const unsigned int*)&qkv[qoff];
  const float c = fcos[n * 32 + dp], s = fsin[n * 32 + dp];
  const float qa = bf2f(qp & 0xffffu), qb = bf2f(qp >> 16);
  const unsigned int qo = f2bf(KL * (qa * c - qb * s)) | (f2bf(KL * (qa * s + qb * c)) << 16);
  const size_t o = ((size_t)((b * Hc + h) * Nc) + n) * Dhc + dp * 2;
  *(unsigned int*)&Qo[o] = qo;
}

// ---------------------------------------------------------------------------
// pack_kv: per (bh, 64-n tile) build the COALESCED attention layouts:
//   Kc[bh][ch=0..7][n][8]  (d-chunk-major K, rope applied here)
//   Vc[bh][g=n>>3][d][8]   (kv-chunk-major V^T)
// ---------------------------------------------------------------------------
__global__ __launch_bounds__(256) void pack_kv(const unsigned short* __restrict__ qkv,
                                               const float* __restrict__ fcos,
                                               const float* __restrict__ fsin,
                                               unsigned short* __restrict__ Kc,
                                               unsigned short* __restrict__ Vc) {
  __shared__ unsigned short kt[64 * 72];  // rows padded to 72 shorts
  __shared__ unsigned short vt[64 * 72];
  const int nt = blockIdx.x, bh = blockIdx.y;
  const int b = bh / Hc, h = bh % Hc;
  const int n0 = nt * 64;
  const int tid = threadIdx.x;
  const int nl = tid >> 3, slot = tid & 7;

#pragma unroll
  for (int it = 0; it < 2; ++it) {
    const int n = it * 32 + nl;
    const size_t base = (size_t)(b * Nc + n0 + n) * K3c + h * 64 + slot * 8;
    i32x4 vv = *(const i32x4*)&qkv[base + 2 * Cc];
    *(i32x4*)&vt[n * 72 + slot * 8] = vv;
    i32x4 kv = *(const i32x4*)&qkv[base + Cc];
    const f32x4 cv = *(const f32x4*)&fcos[(n0 + n) * 32 + slot * 4];
    const f32x4 sv = *(const f32x4*)&fsin[(n0 + n) * 32 + slot * 4];
    i32x4 ko;
    ko.x = (int)rope_pair((unsigned int)kv.x, cv.x, sv.x);
    ko.y = (int)rope_pair((unsigned int)kv.y, cv.y, sv.y);
    ko.z = (int)rope_pair((unsigned int)kv.z, cv.z, sv.z);
    ko.w = (int)rope_pair((unsigned int)kv.w, cv.w, sv.w);
    *(i32x4*)&kt[n * 72 + slot * 8] = ko;
  }
  __syncthreads();

#pragma unroll
  for (int it = 0; it < 2; ++it) {
    const int task = it * 256 + tid;
    const int g = task >> 6;       // 0..7
    const int d = task & 63;       // 0..63
    unsigned short tmpv[8];
#pragma unroll
    for (int j = 0; j < 8; ++j) tmpv[j] = vt[(g * 8 + j) * 72 + d];
    *(i32x4*)&Vc[(((size_t)bh * 256 + (n0 >> 3) + g) * 64 + d) * 8] = *(const i32x4*)tmpv;
    *(i32x4*)&Kc[(((size_t)bh * 8 + g) * Nc + n0 + d) * 8] = *(const i32x4*)&kt[d * 72 + g * 8];
  }
}

// ---------------------------------------------------------------------------
// Causal flash attention — R6 body (best measured: 50.7us, FETCH-optimal
// KV sharing across the 4 waves of a 128-row qtile) with a DECORRELATED
// block mapping. R6's grid (16,48) put the SAME qtile on all 3 blocks a CU
// receives round-robin (256 % 16 == 0) -> some CUs got 3x 32-iter blocks
// (makespan), others 3x 1-iter. New bijection: g=id>>8, c=id&255, u=c>>4,
// v=c&15 -> bh=3u+g, qtile=(v+u+5g)&15. A CU's triple {c,c+256,c+512} now
// has qtiles {w, w+5, w+10} mod 16: exactly one heavy block max per CU
// (48 qtile-15 blocks land on 48 distinct CUs), each co-resident with a
// medium + light block that retire early and free SIMD slots for the tail.
// ---------------------------------------------------------------------------
__global__ __launch_bounds__(256, 3) void attn_fwd(const unsigned short* __restrict__ Qp,
                                                   const unsigned short* __restrict__ Kcp,
                                                   const unsigned short* __restrict__ Vcp,
                                                   unsigned short* __restrict__ Op) {
  const int id = blockIdx.x;
  const int g = id >> 8;                // 0..2
  const int c = id & 255;
  const int u = c >> 4, v = c & 15;
  const int bh = 3 * u + g;             // 0..47
  const int qtile = (v + u + 5 * g) & 15;
  const int tid = threadIdx.x, w = tid >> 6, lane = tid & 63;
  const int qc = lane & 31, hi = lane >> 5;
  const int qw0 = qtile * 128 + w * 32; // wave's first q-row
  const int qrow = qw0 + qc;            // this lane's q index
  const int qwmax = qw0 + 31;
  const unsigned short* Kcb = Kcp + (size_t)bh * (8 * Nc * 8);
  const unsigned short* Vcb = Vcp + (size_t)bh * (256 * 64 * 8);

  bf16x8 qf[4];
  {
    const unsigned short* qptr = Qp + ((size_t)bh * Nc + qrow) * 64 + hi * 8;
#pragma unroll
    for (int ks = 0; ks < 4; ++ks) qf[ks] = *(const bf16x8*)(qptr + ks * 16);
  }

  f32x16 oacc[2];
#pragma unroll
  for (int dt = 0; dt < 2; ++dt)
#pragma unroll
    for (int j = 0; j < 16; ++j) oacc[dt][j] = 0.f;
  float m_run = -1e30f, l_run = 0.f;

  for (int k0 = 0; k0 <= qwmax; k0 += 64) {
    // --- K fragments (coalesced: lanes qc contiguous 16B -> 512B runs;
    //     the block's 4 waves stream overlapping tiles -> L1 reuse)
    bf16x8 kf[2][4];
#pragma unroll
    for (int f = 0; f < 2; ++f)
#pragma unroll
      for (int ks = 0; ks < 4; ++ks)
        kf[f][ks] = *(const bf16x8*)&Kcb[(((2 * ks + hi) * Nc) + k0 + f * 32 + qc) * 8];

    // --- V fragments (coalesced), issued before QK^T so latency hides
    bf16x8 vf[2][4];
#pragma unroll
    for (int dt = 0; dt < 2; ++dt)
#pragma unroll
      for (int ks = 0; ks < 4; ++ks)
        vf[dt][ks] = *(const bf16x8*)&Vcb[(((k0 >> 3) + 2 * ks + hi) * 64 + dt * 32 + qc) * 8];

    // --- QK^T : S^T[kv][q] (already in exp2 domain; Q pre-scaled)
    f32x16 sacc[2];
#pragma unroll
    for (int f = 0; f < 2; ++f)
#pragma unroll
      for (int j = 0; j < 16; ++j) sacc[f][j] = 0.f;
#pragma unroll
    for (int f = 0; f < 2; ++f)
#pragma unroll
      for (int ks = 0; ks < 4; ++ks)
        sacc[f] = __builtin_amdgcn_mfma_f32_32x32x16_bf16(kf[f][ks], qf[ks], sacc[f], 0, 0, 0);

    // --- causal mask folded into sacc; lane kv row: f*32+(rr&3)+8*(rr>>2)+4*hi
    if (k0 + 63 > qw0) {
#pragma unroll
      for (int f = 0; f < 2; ++f)
#pragma unroll
        for (int rr = 0; rr < 16; ++rr) {
          const int kvi = k0 + f * 32 + (rr & 3) + ((rr >> 2) << 3) + (hi << 2);
          if (kvi > qrow) sacc[f][rr] = -1e30f;
        }
    }

    // --- online softmax: tree max
    float mx[16];
#pragma unroll
    for (int j = 0; j < 16; ++j) mx[j] = fmaxf(sacc[0][j], sacc[1][j]);
#pragma unroll
    for (int st = 8; st >= 1; st >>= 1)
#pragma unroll
      for (int j = 0; j < st; ++j) mx[j] = fmaxf(mx[j], mx[j + st]);
    const float pmax = fmaxf(mx[0], __shfl_xor(mx[0], 32, 64));

    if (!__all(pmax - m_run <= 11.5f)) {  // defer-max (T13)
      const float m_new = fmaxf(m_run, pmax);
      const float rs = EXP2(m_run - m_new);
      l_run *= rs;
#pragma unroll
      for (int dt = 0; dt < 2; ++dt)
#pragma unroll
        for (int j = 0; j < 16; ++j) oacc[dt][j] *= rs;
      m_run = m_new;
    }

    // --- P = exp2(S - m); masked entries underflow to 0
    float p[32];
#pragma unroll
    for (int f = 0; f < 2; ++f)
#pragma unroll
      for (int rr = 0; rr < 16; ++rr) p[f * 16 + rr] = EXP2(sacc[f][rr] - m_run);

    // tree sum
    float ts[16];
#pragma unroll
    for (int j = 0; j < 16; ++j) ts[j] = p[j] + p[16 + j];
#pragma unroll
    for (int st = 8; st >= 1; st >>= 1)
#pragma unroll
      for (int j = 0; j < st; ++j) ts[j] += ts[j + st];
    l_run += ts[0] + __shfl_xor(ts[0], 32, 64);

    unsigned int pw[2][8];
#pragma unroll
    for (int f = 0; f < 2; ++f) {
#pragma unroll
      for (int j = 0; j < 8; ++j)
        pw[f][j] = cvtpk_bf16(p[f * 16 + 2 * j], p[f * 16 + 2 * j + 1]);
      // T12: earlier-kv word is vdst (vdst[32:63] <-> vsrc[0:31])
      asm volatile("v_permlane32_swap_b32 %0, %1" : "+v"(pw[f][0]), "+v"(pw[f][2]));
      asm volatile("v_permlane32_swap_b32 %0, %1" : "+v"(pw[f][1]), "+v"(pw[f][3]));
      asm volatile("v_permlane32_swap_b32 %0, %1" : "+v"(pw[f][4]), "+v"(pw[f][6]));
      asm volatile("v_permlane32_swap_b32 %0, %1" : "+v"(pw[f][5]), "+v"(pw[f][7]));
    }

    // --- PV: O^T[d][q] += V^T x P
#pragma unroll
    for (int dt = 0; dt < 2; ++dt)
#pragma unroll
      for (int ks = 0; ks < 4; ++ks) {
        i32x4 pi;
        pi.x = (int)pw[ks >> 1][(ks & 1) * 4 + 0];
        pi.y = (int)pw[ks >> 1][(ks & 1) * 4 + 1];
        pi.z = (int)pw[ks >> 1][(ks & 1) * 4 + 2];
        pi.w = (int)pw[ks >> 1][(ks & 1) * 4 + 3];
        bf16x8 pf = __builtin_bit_cast(bf16x8, pi);
        oacc[dt] = __builtin_amdgcn_mfma_f32_32x32x16_bf16(vf[dt][ks], pf, oacc[dt], 0, 0, 0);
      }
  }

  // --- epilogue: lane owns q column; d = dt*32 + rq*8 + hi*4 + (0..3)
  const float inv = 1.f / l_run;
  const int b = bh / Hc, h = bh % Hc;
  unsigned short* orow = Op + ((size_t)(b * Nc + qrow)) * Cc + h * 64;
#pragma unroll
  for (int dt = 0; dt < 2; ++dt)
#pragma unroll
    for (int rq = 0; rq < 4; ++rq) {
      const float o0 = oacc[dt][rq * 4 + 0] * inv;
      const float o1 = oacc[dt][rq * 4 + 1] * inv;
      const float o2 = oacc[dt][rq * 4 + 2] * inv;
      const float o3 = oacc[dt][rq * 4 + 3] * inv;
      uint2 val;
      val.x = f2bf(o0) | (f2bf(o1) << 16);
      val.y = f2bf(o2) | (f2bf(o3) << 16);
      *(uint2*)(orow + dt * 32 + rq * 8 + hi * 4) = val;
    }
}

// ---------------------------------------------------------------------------
// Workspace layout (75,497,472 B total):
//   [0,       37.75M) qkv bf16          (later reused as attn output)
//   [37.75M, +12.58M) x_bf16, then Q    (x dead before rope_q writes Q)
//   [50.33M, +12.58M) wqkv_bf16, then Kc (wqkv dead before pack_kv)
//   [62.91M, +12.58M) Vc, then wproj_bf16 after attn consumes Vc
// ---------------------------------------------------------------------------
extern "C" void kernel_launch(void* const* d_in, const int* in_sizes, int n_in,
                              void* d_out, int out_size, void* d_ws, size_t ws_size,
                              hipStream_t stream) {
  const float* x = (const float*)d_in[0];
  const float* fcos = (const float*)d_in[1];
  const float* fsin = (const float*)d_in[2];
  // d_in[3] (mask) unused: causal structure applied analytically
  const float* wqkv = (const float*)d_in[4];
  const float* wproj = (const float*)d_in[5];
  const float* bproj = (const float*)d_in[6];

  char* ws = (char*)d_ws;
  unsigned short* qkvb = (unsigned short*)ws;
  unsigned short* Qb = (unsigned short*)(ws + 37748736);
  unsigned short* Kcb = (unsigned short*)(ws + 37748736 + 12582912);
  unsigned short* Vcb = (unsigned short*)(ws + 37748736 + 2 * 12582912);
  unsigned short* xb = Qb;
  unsigned short* wqkvb = Kcb;
  unsigned short* wprojb = (unsigned short*)(ws + 37748736);  // shares Q region tail?
  // NOTE: wproj_bf16 must not alias Q (Q live during attn). Place it in the
  // qkv region's tail: qkv buffer is 37.75MB, attn output needs only
  // 12.58MB at offset 0 — put wproj_bf16 at qkv + 24MB (dead qkv space).
  wprojb = (unsigned short*)(ws + 25165824);
  unsigned short* attnb = qkvb;

  // 0. fp32 -> bf16 converts
  cvt_f32_bf16<<<dim3(786432 / 256), 256, 0, stream>>>(x, xb, 786432);
  cvt_f32_bf16<<<dim3(221184 / 256), 256, 0, stream>>>(wqkv, wqkvb, 221184);
  // 1. qkv = x @ w_qkv^T (bf16 out)
  gemm_bt16<1><<<dim3(K3c / 128, Mc / 128), 256, 0, stream>>>(xb, wqkvb, qkvb, nullptr,
                                                              K3c, Cc);
  // 2. RoPE -> Q [B,H,N,Dh] (pre-scaled by KL)
  rope_q<<<dim3(Bc * Nc * Hc * 32 / 256), 256, 0, stream>>>(qkvb, fcos, fsin, Qb);
  // 3. K-rope + chunk-major packs -> Kc, Vc
  pack_kv<<<dim3(Nc / 64, Bc * Hc), 256, 0, stream>>>(qkvb, fcos, fsin, Kcb, Vcb);
  // 3b. proj-weight convert (independent — overlaps with attn head start;
  //     destination is dead qkv space at +24MB, NOT the attn output region)
  cvt_f32_bf16<<<dim3(73728 / 256), 256, 0, stream>>>(wproj, wprojb, 73728);
  // 4. causal attention -> attnb [B,N,C] bf16 at ws+0 (768 blocks,
  //    decorrelated qtile mapping)
  attn_fwd<<<dim3(768), 256, 0, stream>>>(Qb, Kcb, Vcb, attnb);
  // 5. out = attn @ w_proj^T + b (fp32 out)
  gemm_bt16<0><<<dim3(Cc / 128, Mc / 128), 256, 0, stream>>>(attnb, wprojb, d_out, bproj,
                                                             Cc, Cc);
}

// Round 13
// 147.605 us; speedup vs baseline: 1.0615x; 1.0382x over previous
//
#include <hip/hip_runtime.h>
#include <hip/hip_bf16.h>

#define DEVI static __device__ __forceinline__

typedef __attribute__((ext_vector_type(8))) short bf16x8;
typedef __attribute__((ext_vector_type(4))) float f32x4;
typedef __attribute__((ext_vector_type(16))) float f32x16;
typedef __attribute__((ext_vector_type(4))) int i32x4;

constexpr int Bc = 4, Nc = 2048, Cc = 768, Hc = 12, Dhc = 64;
constexpr int Mc = Bc * Nc;   // 8192 tokens
constexpr int K3c = 3 * Cc;   // 2304

// fp32 -> bf16 round-to-nearest-even
DEVI unsigned int f2bf(float f) {
  unsigned int u = __float_as_uint(f);
  return (u + 0x7fffu + ((u >> 16) & 1u)) >> 16;
}
DEVI float bf2f(unsigned int u) { return __uint_as_float(u << 16); }

DEVI unsigned int cvtpk_bf16(float lo, float hi_) {
  unsigned int r;
  asm("v_cvt_pk_bf16_f32 %0, %1, %2" : "=v"(r) : "v"(lo), "v"(hi_));
  return r;
}

// Raw v_exp_f32 (2^x) — libm exp2f is a multi-inst OCML routine (round-4 bug).
#if __has_builtin(__builtin_amdgcn_exp2f)
#define EXP2(x) __builtin_amdgcn_exp2f(x)
#else
#define EXP2(x) exp2f(x)
#endif

#define GLOAD_LDS(g, l)                                                              \
  __builtin_amdgcn_global_load_lds((const __attribute__((address_space(1))) void*)(g), \
                                   (__attribute__((address_space(3))) void*)(l), 16, 0, 0)

// rope on a packed bf16 pair word
DEVI unsigned int rope_pair(unsigned int w, float c, float s) {
  const float a = bf2f(w & 0xffffu), b_ = bf2f(w >> 16);
  return f2bf(a * c - b_ * s) | (f2bf(a * s + b_ * c) << 16);
}

// ---------------------------------------------------------------------------
// fp32 -> bf16 bulk convert, 8 elems/thread
// ---------------------------------------------------------------------------
__global__ __launch_bounds__(256) void cvt_f32_bf16(const float* __restrict__ in,
                                                    unsigned short* __restrict__ out, int n8) {
  const int i = blockIdx.x * 256 + threadIdx.x;
  if (i >= n8) return;
  const f32x4 a = *((const f32x4*)in + (size_t)i * 2);
  const f32x4 b = *((const f32x4*)in + (size_t)i * 2 + 1);
  i32x4 v;
  v.x = (int)(f2bf(a.x) | (f2bf(a.y) << 16));
  v.y = (int)(f2bf(a.z) | (f2bf(a.w) << 16));
  v.z = (int)(f2bf(b.x) | (f2bf(b.y) << 16));
  v.w = (int)(f2bf(b.z) | (f2bf(b.w) << 16));
  *((i32x4*)out + i) = v;
}

// ---------------------------------------------------------------------------
// GEMM: C[M,Nout] = A[M,K] * W[Nout,K]^T, bf16 in. 128x128 tile, BK=64,
// 4 waves (2x2), mfma 16x16x32, global_load_lds staging.
// Round-13: T1 XCD-aware block swizzle. 1D grid = 8*8*nbn blocks:
// xcd = id&7, j = id>>3, bm = xcd*8 + j/nbn, bn = j%nbn. Each XCD owns 8
// contiguous bm rows (A panel 1.57MB) x all bn (B <= 3.5MB) -> working set
// ~L2-resident; B re-reads become L2 hits instead of L3/HBM streams.
// ---------------------------------------------------------------------------
template <int OBF16>
__global__ __launch_bounds__(256) void gemm_bt16(const unsigned short* __restrict__ Ap,
                                                 const unsigned short* __restrict__ Wp,
                                                 void* __restrict__ Cp,
                                                 const float* __restrict__ bias,
                                                 int Nout, int Kdim, int nbn) {
  __shared__ unsigned short As[128 * 64];
  __shared__ unsigned short Bs[128 * 64];
  const int tid = threadIdx.x;
  const int id = blockIdx.x;
  const int j = id >> 3;
  const int jq = j / nbn;
  const int bm = (id & 7) * 8 + jq;
  const int bn = j - jq * nbn;
  const int m0 = bm * 128, n0 = bn * 128;
  const int w = tid >> 6, lane = tid & 63;
  const int wr = w >> 1, wc = w & 1;
  const int lr = lane & 15, lg = lane >> 4;
  const int r = lane >> 3, slot = lane & 7;

  f32x4 acc[4][4];
#pragma unroll
  for (int i = 0; i < 4; ++i)
#pragma unroll
    for (int jj = 0; jj < 4; ++jj) acc[i][jj] = f32x4{0.f, 0.f, 0.f, 0.f};

  for (int kt = 0; kt < Kdim; kt += 64) {
    __syncthreads();
#pragma unroll
    for (int c = 0; c < 4; ++c) {
      const int i = (w << 2) + c;
      const int row = (i << 3) + r;
      const unsigned short* ga = Ap + (size_t)(m0 + row) * Kdim + kt + ((slot ^ r) << 3);
      GLOAD_LDS(ga, As + (i << 9));
      const unsigned short* gb = Wp + (size_t)(n0 + row) * Kdim + kt + ((slot ^ r) << 3);
      GLOAD_LDS(gb, Bs + (i << 9));
    }
    __syncthreads();

    bf16x8 af[4][2], bfr[4][2];
#pragma unroll
    for (int mf = 0; mf < 4; ++mf) {
      const int row = wr * 64 + mf * 16 + lr;
#pragma unroll
      for (int kk = 0; kk < 2; ++kk)
        af[mf][kk] = *(const bf16x8*)&As[row * 64 + (((kk * 4 + lg) ^ (row & 7)) * 8)];
    }
#pragma unroll
    for (int nf = 0; nf < 4; ++nf) {
      const int row = wc * 64 + nf * 16 + lr;
#pragma unroll
      for (int kk = 0; kk < 2; ++kk)
        bfr[nf][kk] = *(const bf16x8*)&Bs[row * 64 + (((kk * 4 + lg) ^ (row & 7)) * 8)];
    }
#pragma unroll
    for (int mf = 0; mf < 4; ++mf)
#pragma unroll
      for (int nf = 0; nf < 4; ++nf)
#pragma unroll
        for (int kk = 0; kk < 2; ++kk)
          acc[mf][nf] = __builtin_amdgcn_mfma_f32_16x16x32_bf16(af[mf][kk], bfr[nf][kk],
                                                                acc[mf][nf], 0, 0, 0);
  }

#pragma unroll
  for (int mf = 0; mf < 4; ++mf) {
#pragma unroll
    for (int nf = 0; nf < 4; ++nf) {
      const int col = n0 + wc * 64 + nf * 16 + lr;
#pragma unroll
      for (int rg = 0; rg < 4; ++rg) {
        const int rowg = m0 + wr * 64 + mf * 16 + lg * 4 + rg;
        const float v = acc[mf][nf][rg];
        if constexpr (OBF16) {
          ((unsigned short*)Cp)[(size_t)rowg * Nout + col] = (unsigned short)f2bf(v);
        } else {
          ((float*)Cp)[(size_t)rowg * Nout + col] = v + bias[col];
        }
      }
    }
  }
}

// ---------------------------------------------------------------------------
// RoPE for Q only: qkv [B,N,3,H,Dh] bf16 -> Q [B,H,N,Dh] bf16, pre-scaled
// by KL = (1/sqrt(Dh))*log2(e). (K handled in pack_kv.)
// ---------------------------------------------------------------------------
__global__ __launch_bounds__(256) void rope_q(const unsigned short* __restrict__ qkv,
                                              const float* __restrict__ fcos,
                                              const float* __restrict__ fsin,
                                              unsigned short* __restrict__ Qo) {
  constexpr float KL = 0.18033688011112042f;  // (1/sqrt(64)) * log2(e)
  const int idx = blockIdx.x * 256 + threadIdx.x;
  if (idx >= Bc * Nc * Hc * 32) return;
  const int dp = idx & 31;
  const int t = idx >> 5;
  const int h = t % Hc;
  const int bn = t / Hc;
  const int n = bn & (Nc - 1);
  const int b = bn >> 11;
  const size_t qoff = (size_t)bn * 3 * Cc + h * 64 + dp * 2;
  const unsigned int qp = *(const unsigned int*)&qkv[qoff];
  const float c = fcos[n * 32 + dp], s = fsin[n * 32 + dp];
  const float qa = bf2f(qp & 0xffffu), qb = bf2f(qp >> 16);
  const unsigned int qo = f2bf(KL * (qa * c - qb * s)) | (f2bf(KL * (qa * s + qb * c)) << 16);
  const size_t o = ((size_t)((b * Hc + h) * Nc) + n) * Dhc + dp * 2;
  *(unsigned int*)&Qo[o] = qo;
}

// ---------------------------------------------------------------------------
// pack_kv: per (bh, 64-n tile) build the COALESCED attention layouts:
//   Kc[bh][ch=0..7][n][8]  (d-chunk-major K, rope applied here)
//   Vc[bh][g=n>>3][d][8]   (kv-chunk-major V^T)
// ---------------------------------------------------------------------------
__global__ __launch_bounds__(256) void pack_kv(const unsigned short* __restrict__ qkv,
                                               const float* __restrict__ fcos,
                                               const float* __restrict__ fsin,
                                               unsigned short* __restrict__ Kc,
                                               unsigned short* __restrict__ Vc) {
  __shared__ unsigned short kt[64 * 72];  // rows padded to 72 shorts
  __shared__ unsigned short vt[64 * 72];
  const int nt = blockIdx.x, bh = blockIdx.y;
  const int b = bh / Hc, h = bh % Hc;
  const int n0 = nt * 64;
  const int tid = threadIdx.x;
  const int nl = tid >> 3, slot = tid & 7;

#pragma unroll
  for (int it = 0; it < 2; ++it) {
    const int n = it * 32 + nl;
    const size_t base = (size_t)(b * Nc + n0 + n) * K3c + h * 64 + slot * 8;
    i32x4 vv = *(const i32x4*)&qkv[base + 2 * Cc];
    *(i32x4*)&vt[n * 72 + slot * 8] = vv;
    i32x4 kv = *(const i32x4*)&qkv[base + Cc];
    const f32x4 cv = *(const f32x4*)&fcos[(n0 + n) * 32 + slot * 4];
    const f32x4 sv = *(const f32x4*)&fsin[(n0 + n) * 32 + slot * 4];
    i32x4 ko;
    ko.x = (int)rope_pair((unsigned int)kv.x, cv.x, sv.x);
    ko.y = (int)rope_pair((unsigned int)kv.y, cv.y, sv.y);
    ko.z = (int)rope_pair((unsigned int)kv.z, cv.z, sv.z);
    ko.w = (int)rope_pair((unsigned int)kv.w, cv.w, sv.w);
    *(i32x4*)&kt[n * 72 + slot * 8] = ko;
  }
  __syncthreads();

#pragma unroll
  for (int it = 0; it < 2; ++it) {
    const int task = it * 256 + tid;
    const int g = task >> 6;       // 0..7
    const int d = task & 63;       // 0..63
    unsigned short tmpv[8];
#pragma unroll
    for (int jj = 0; jj < 8; ++jj) tmpv[jj] = vt[(g * 8 + jj) * 72 + d];
    *(i32x4*)&Vc[(((size_t)bh * 256 + (n0 >> 3) + g) * 64 + d) * 8] = *(const i32x4*)tmpv;
    *(i32x4*)&Kc[(((size_t)bh * 8 + g) * Nc + n0 + d) * 8] = *(const i32x4*)&kt[d * 72 + g * 8];
  }
}

// ---------------------------------------------------------------------------
// Causal flash attention — R6 body (best: 50.7us) with a mapping that keeps
// BOTH properties:
//  (a) L2/L3 locality: bh = id>>4 (16 consecutive ids share one bh, as R6;
//      R12's scattered bh blew FETCH 18.5->83MB),
//  (b) CU balance: qtile = (v + 5*(bh%3)) & 15. The CU-resident triple
//      {c, c+256, c+512} has bh differing by 16 and 16 = 1 mod 3, so the
//      qtile shifts are {0,5,10} -> triple iteration sums in [40,66] vs
//      R6's [6,96] (one CU could hold three 32-iter blocks).
// Bijective: per-bh the shift is constant mod 16.
// ---------------------------------------------------------------------------
__global__ __launch_bounds__(256, 3) void attn_fwd(const unsigned short* __restrict__ Qp,
                                                   const unsigned short* __restrict__ Kcp,
                                                   const unsigned short* __restrict__ Vcp,
                                                   unsigned short* __restrict__ Op) {
  const int id = blockIdx.x;
  const int bh = id >> 4;               // 0..47 (R6 locality)
  const int v = id & 15;
  const int qtile = (v + 5 * (bh % 3)) & 15;
  const int tid = threadIdx.x, w = tid >> 6, lane = tid & 63;
  const int qc = lane & 31, hi = lane >> 5;
  const int qw0 = qtile * 128 + w * 32; // wave's first q-row
  const int qrow = qw0 + qc;            // this lane's q index
  const int qwmax = qw0 + 31;
  const unsigned short* Kcb = Kcp + (size_t)bh * (8 * Nc * 8);
  const unsigned short* Vcb = Vcp + (size_t)bh * (256 * 64 * 8);

  bf16x8 qf[4];
  {
    const unsigned short* qptr = Qp + ((size_t)bh * Nc + qrow) * 64 + hi * 8;
#pragma unroll
    for (int ks = 0; ks < 4; ++ks) qf[ks] = *(const bf16x8*)(qptr + ks * 16);
  }

  f32x16 oacc[2];
#pragma unroll
  for (int dt = 0; dt < 2; ++dt)
#pragma unroll
    for (int jj = 0; jj < 16; ++jj) oacc[dt][jj] = 0.f;
  float m_run = -1e30f, l_run = 0.f;

  for (int k0 = 0; k0 <= qwmax; k0 += 64) {
    // --- K fragments (coalesced: lanes qc contiguous 16B -> 512B runs;
    //     the block's 4 waves stream overlapping tiles -> L1 reuse)
    bf16x8 kf[2][4];
#pragma unroll
    for (int f = 0; f < 2; ++f)
#pragma unroll
      for (int ks = 0; ks < 4; ++ks)
        kf[f][ks] = *(const bf16x8*)&Kcb[(((2 * ks + hi) * Nc) + k0 + f * 32 + qc) * 8];

    // --- V fragments (coalesced), issued before QK^T so latency hides
    bf16x8 vf[2][4];
#pragma unroll
    for (int dt = 0; dt < 2; ++dt)
#pragma unroll
      for (int ks = 0; ks < 4; ++ks)
        vf[dt][ks] = *(const bf16x8*)&Vcb[(((k0 >> 3) + 2 * ks + hi) * 64 + dt * 32 + qc) * 8];

    // --- QK^T : S^T[kv][q] (already in exp2 domain; Q pre-scaled)
    f32x16 sacc[2];
#pragma unroll
    for (int f = 0; f < 2; ++f)
#pragma unroll
      for (int jj = 0; jj < 16; ++jj) sacc[f][jj] = 0.f;
#pragma unroll
    for (int f = 0; f < 2; ++f)
#pragma unroll
      for (int ks = 0; ks < 4; ++ks)
        sacc[f] = __builtin_amdgcn_mfma_f32_32x32x16_bf16(kf[f][ks], qf[ks], sacc[f], 0, 0, 0);

    // --- causal mask folded into sacc; lane kv row: f*32+(rr&3)+8*(rr>>2)+4*hi
    if (k0 + 63 > qw0) {
#pragma unroll
      for (int f = 0; f < 2; ++f)
#pragma unroll
        for (int rr = 0; rr < 16; ++rr) {
          const int kvi = k0 + f * 32 + (rr & 3) + ((rr >> 2) << 3) + (hi << 2);
          if (kvi > qrow) sacc[f][rr] = -1e30f;
        }
    }

    // --- online softmax: tree max
    float mx[16];
#pragma unroll
    for (int jj = 0; jj < 16; ++jj) mx[jj] = fmaxf(sacc[0][jj], sacc[1][jj]);
#pragma unroll
    for (int st = 8; st >= 1; st >>= 1)
#pragma unroll
      for (int jj = 0; jj < st; ++jj) mx[jj] = fmaxf(mx[jj], mx[jj + st]);
    const float pmax = fmaxf(mx[0], __shfl_xor(mx[0], 32, 64));

    if (!__all(pmax - m_run <= 11.5f)) {  // defer-max (T13)
      const float m_new = fmaxf(m_run, pmax);
      const float rs = EXP2(m_run - m_new);
      l_run *= rs;
#pragma unroll
      for (int dt = 0; dt < 2; ++dt)
#pragma unroll
        for (int jj = 0; jj < 16; ++jj) oacc[dt][jj] *= rs;
      m_run = m_new;
    }

    // --- P = exp2(S - m); masked entries underflow to 0
    float p[32];
#pragma unroll
    for (int f = 0; f < 2; ++f)
#pragma unroll
      for (int rr = 0; rr < 16; ++rr) p[f * 16 + rr] = EXP2(sacc[f][rr] - m_run);

    // tree sum
    float ts[16];
#pragma unroll
    for (int jj = 0; jj < 16; ++jj) ts[jj] = p[jj] + p[16 + jj];
#pragma unroll
    for (int st = 8; st >= 1; st >>= 1)
#pragma unroll
      for (int jj = 0; jj < st; ++jj) ts[jj] += ts[jj + st];
    l_run += ts[0] + __shfl_xor(ts[0], 32, 64);

    unsigned int pw[2][8];
#pragma unroll
    for (int f = 0; f < 2; ++f) {
#pragma unroll
      for (int jj = 0; jj < 8; ++jj)
        pw[f][jj] = cvtpk_bf16(p[f * 16 + 2 * jj], p[f * 16 + 2 * jj + 1]);
      // T12: earlier-kv word is vdst (vdst[32:63] <-> vsrc[0:31])
      asm volatile("v_permlane32_swap_b32 %0, %1" : "+v"(pw[f][0]), "+v"(pw[f][2]));
      asm volatile("v_permlane32_swap_b32 %0, %1" : "+v"(pw[f][1]), "+v"(pw[f][3]));
      asm volatile("v_permlane32_swap_b32 %0, %1" : "+v"(pw[f][4]), "+v"(pw[f][6]));
      asm volatile("v_permlane32_swap_b32 %0, %1" : "+v"(pw[f][5]), "+v"(pw[f][7]));
    }

    // --- PV: O^T[d][q] += V^T x P
#pragma unroll
    for (int dt = 0; dt < 2; ++dt)
#pragma unroll
      for (int ks = 0; ks < 4; ++ks) {
        i32x4 pi;
        pi.x = (int)pw[ks >> 1][(ks & 1) * 4 + 0];
        pi.y = (int)pw[ks >> 1][(ks & 1) * 4 + 1];
        pi.z = (int)pw[ks >> 1][(ks & 1) * 4 + 2];
        pi.w = (int)pw[ks >> 1][(ks & 1) * 4 + 3];
        bf16x8 pf = __builtin_bit_cast(bf16x8, pi);
        oacc[dt] = __builtin_amdgcn_mfma_f32_32x32x16_bf16(vf[dt][ks], pf, oacc[dt], 0, 0, 0);
      }
  }

  // --- epilogue: lane owns q column; d = dt*32 + rq*8 + hi*4 + (0..3)
  const float inv = 1.f / l_run;
  const int b = bh / Hc, h = bh % Hc;
  unsigned short* orow = Op + ((size_t)(b * Nc + qrow)) * Cc + h * 64;
#pragma unroll
  for (int dt = 0; dt < 2; ++dt)
#pragma unroll
    for (int rq = 0; rq < 4; ++rq) {
      const float o0 = oacc[dt][rq * 4 + 0] * inv;
      const float o1 = oacc[dt][rq * 4 + 1] * inv;
      const float o2 = oacc[dt][rq * 4 + 2] * inv;
      const float o3 = oacc[dt][rq * 4 + 3] * inv;
      uint2 val;
      val.x = f2bf(o0) | (f2bf(o1) << 16);
      val.y = f2bf(o2) | (f2bf(o3) << 16);
      *(uint2*)(orow + dt * 32 + rq * 8 + hi * 4) = val;
    }
}

// ---------------------------------------------------------------------------
// Workspace layout (75,497,472 B total):
//   [0,       37.75M) qkv bf16; attn output reuses [0,12.58M);
//                     wproj_bf16 at +24MB (dead qkv space, non-aliasing)
//   [37.75M, +12.58M) x_bf16, then Q    (x dead before rope_q writes Q)
//   [50.33M, +12.58M) wqkv_bf16, then Kc (wqkv dead before pack_kv)
//   [62.91M, +12.58M) Vc
// ---------------------------------------------------------------------------
extern "C" void kernel_launch(void* const* d_in, const int* in_sizes, int n_in,
                              void* d_out, int out_size, void* d_ws, size_t ws_size,
                              hipStream_t stream) {
  const float* x = (const float*)d_in[0];
  const float* fcos = (const float*)d_in[1];
  const float* fsin = (const float*)d_in[2];
  // d_in[3] (mask) unused: causal structure applied analytically
  const float* wqkv = (const float*)d_in[4];
  const float* wproj = (const float*)d_in[5];
  const float* bproj = (const float*)d_in[6];

  char* ws = (char*)d_ws;
  unsigned short* qkvb = (unsigned short*)ws;
  unsigned short* Qb = (unsigned short*)(ws + 37748736);
  unsigned short* Kcb = (unsigned short*)(ws + 37748736 + 12582912);
  unsigned short* Vcb = (unsigned short*)(ws + 37748736 + 2 * 12582912);
  unsigned short* xb = Qb;
  unsigned short* wqkvb = Kcb;
  unsigned short* wprojb = (unsigned short*)(ws + 25165824);
  unsigned short* attnb = qkvb;

  // 0. fp32 -> bf16 converts
  cvt_f32_bf16<<<dim3(786432 / 256), 256, 0, stream>>>(x, xb, 786432);
  cvt_f32_bf16<<<dim3(221184 / 256), 256, 0, stream>>>(wqkv, wqkvb, 221184);
  // 1. qkv = x @ w_qkv^T (bf16 out; XCD-swizzled grid: 8*8*18 = 1152)
  gemm_bt16<1><<<dim3(1152), 256, 0, stream>>>(xb, wqkvb, qkvb, nullptr, K3c, Cc, 18);
  // 2. RoPE -> Q [B,H,N,Dh] (pre-scaled by KL)
  rope_q<<<dim3(Bc * Nc * Hc * 32 / 256), 256, 0, stream>>>(qkvb, fcos, fsin, Qb);
  // 3. K-rope + chunk-major packs -> Kc, Vc
  pack_kv<<<dim3(Nc / 64, Bc * Hc), 256, 0, stream>>>(qkvb, fcos, fsin, Kcb, Vcb);
  // 3b. proj-weight convert (independent; overlaps attn start)
  cvt_f32_bf16<<<dim3(73728 / 256), 256, 0, stream>>>(wproj, wprojb, 73728);
  // 4. causal attention -> attnb (768 blocks; bh-adjacent + qtile-rotated)
  attn_fwd<<<dim3(768), 256, 0, stream>>>(Qb, Kcb, Vcb, attnb);
  // 5. out = attn @ w_proj^T + b (fp32 out; XCD-swizzled grid: 8*8*6 = 384)
  gemm_bt16<0><<<dim3(384), 256, 0, stream>>>(attnb, wprojb, d_out, bproj, Cc, Cc, 6);
}